// Round 3
// baseline (125.259 us; speedup 1.0000x reference)
//
#include <hip/hip_runtime.h>

#define NAG 16
#define SPB 4        // scenes per block, one M=64 batch, single pass
#define NBLK 2048
#define R2f 64.0f

typedef unsigned short u16;
typedef __attribute__((ext_vector_type(8))) short short8;
typedef __attribute__((ext_vector_type(4))) float f32x4;

#define MFMA(a, b, c) __builtin_amdgcn_mfma_f32_16x16x32_bf16(a, b, c, 0, 0, 0)

// ws blob offsets in u16 units
#define OFF_B1 0        // [Wroot1;Wrel1]  K=128 N=128  S=4 T=8  (root s0..1, rel s2..3)
#define OFF_B2 16384    // [Wroot2;Wrel2]  K=256 N=128  S=8 T=8  (root s0..3, rel s4..7) [k-perm]
#define OFF_H1 49152    // Wh1             K=256 N=64   S=8 T=4                          [k-perm]
#define OFF_H2 65536    // Wh2             K=64  N=32   S=2 T=2
#define OFF_H3 67584    // Wh3             K=32  N=16   S=1 T=1
#define SWZ_UNITS 8512

__device__ __forceinline__ u16 f2b(float f) {            // RNE (swizzle only)
    unsigned u = __float_as_uint(f);
    unsigned r = u + 0x7FFFu + ((u >> 16) & 1u);
    return (u16)(r >> 16);
}
// fast round-to-nearest (ties up) — hot-kernel path; sub-ulp delta vs RNE
__device__ __forceinline__ unsigned rb(float f) {
    return (__float_as_uint(f) + 0x8000u) >> 16;
}
__device__ __forceinline__ unsigned pk2(float a, float b) {
    return ((__float_as_uint(a) + 0x8000u) >> 16) |
           ((__float_as_uint(b) + 0x8000u) & 0xFFFF0000u);
}

// ---------------- weight pre-swizzle: W[K][N] f32 -> fragment order bf16 -----
// B2/H1 use a k-permutation matching the pair-packed x1/x2 LDS layout:
// physical col p within each 32-group holds logical channel (p>>1) + 16*(p&1).
__global__ __launch_bounds__(256) void swizzle_w(
    const float* __restrict__ Wrel1, const float* __restrict__ Wroot1,
    const float* __restrict__ Wrel2, const float* __restrict__ Wroot2,
    const float* __restrict__ Wh1,  const float* __restrict__ Wh2,
    const float* __restrict__ Wh3,  u16* __restrict__ ws)
{
    const int u = blockIdx.x * 256 + threadIdx.x;
    if (u >= SWZ_UNITS) return;
    int v, T, N, ksplit;
    bool perm = false;
    const float *W, *W2;
    u16* dst;
    if (u < 2048)      { v = u;        T = 8; N = 128; ksplit = 64;  W = Wroot1; W2 = Wrel1; dst = ws + OFF_B1 + v * 8; }
    else if (u < 6144) { v = u - 2048; T = 8; N = 128; ksplit = 128; W = Wroot2; W2 = Wrel2; dst = ws + OFF_B2 + v * 8; perm = true; }
    else if (u < 8192) { v = u - 6144; T = 4; N = 64;  ksplit = 1 << 30; W = Wh1; W2 = Wh1; dst = ws + OFF_H1 + v * 8; perm = true; }
    else if (u < 8448) { v = u - 8192; T = 2; N = 32;  ksplit = 1 << 30; W = Wh2; W2 = Wh2; dst = ws + OFF_H2 + v * 8; }
    else               { v = u - 8448; T = 1; N = 16;  ksplit = 1 << 30; W = Wh3; W2 = Wh3; dst = ws + OFF_H3 + v * 8; }
    const int lane = v & 63;
    const int t = (v >> 6) % T;
    const int s = (v >> 6) / T;
    const int n = t * 16 + (lane & 15);
    const int k0 = s * 32 + (lane >> 4) * 8;
    #pragma unroll
    for (int j = 0; j < 8; ++j) {
        const int k = k0 + j;
        const int kl = perm ? ((k & ~31) + ((k & 31) >> 1) + ((k & 1) << 4)) : k;
        const float val = (kl < ksplit) ? W[kl * N + n] : W2[(kl - ksplit) * N + n];
        dst[j] = f2b(val);
    }
}

__device__ __forceinline__ short8 ldfrag(const u16* __restrict__ ws, int off,
                                         int T, int s, int tile, int lane) {
    return *(const short8*)(ws + off + (size_t)(((s * T + tile) * 64 + lane) * 8));
}

// adjacency A-fragment, scene g packed in 32-row K window (2 scenes):
// A[m=lane&15][k=q*8+j]; valid only in this scene's half (q>>1 == odd).
__device__ __forceinline__ short8 make_adjA(unsigned m, int q, int odd) {
    union { short8 v; unsigned u[4]; } r;
    const bool on = (q >> 1) == odd;
    const int base = (q & 1) * 8;
    #pragma unroll
    for (int jj = 0; jj < 4; ++jj) {
        const int k0 = base + 2 * jj;
        const unsigned lo = (on && ((m >> k0) & 1u)) ? 0x3F80u : 0u;
        const unsigned hi = (on && ((m >> (k0 + 1)) & 1u)) ? 0x3F80u : 0u;
        r.u[jj] = lo | (hi << 16);
    }
    return r.v;
}

// LDS (u16 units): xb [64][136] (x cols0..63; later x2 cols0..127)   0..8704
//                  yT [128][72] (y^T ch-major; later h1 [64][72])    8704..17920
//                  x1b [64][136] (x1; later h2 [64][40])             17920..26624
// 53 KB total -> 3 blocks/CU. Barriers: S0|L1|L2|GEMM3|GEMM45 = 4.
// LATENCY SCHEDULE (this round): all cold global loads (pos, x) issue at entry;
// each phase's weight fragments are prefetched during the PREVIOUS phase so no
// wave stalls on L2-hit frag loads right after a barrier. Masks are computed
// per-wave from register-resident pos (no serial wave-0 section).
// x1/x2 pair-packed (physical col p = logical (p>>1)+16*(p&1)); B2/H1 k-perm'd.
__global__ __launch_bounds__(256) void gnn_fused5(
    const float* __restrict__ x, const float* __restrict__ pos,
    const float* __restrict__ brel1, const float* __restrict__ brel2,
    const float* __restrict__ bh1,  const float* __restrict__ bh2,
    const float* __restrict__ bh3,
    const u16* __restrict__ ws, float* __restrict__ out)
{
    __shared__ __align__(16) u16 pool[26624];
    __shared__ unsigned mask[64];
    u16* const xb  = pool;          // also x2
    u16* const yT  = pool + 8704;   // also h1
    u16* const x1b = pool + 17920;  // also h2

    const int t = threadIdx.x;
    const int wv = t >> 6, lane = t & 63, ln = lane & 15, q = lane >> 4;
    const int c0 = 32 * wv;                 // wave's output-col base (L1/L2)
    const int n0 = 2 * wv, n1 = 2 * wv + 1;
    const size_t sA = (size_t)blockIdx.x * SPB;

    // ---- P0: issue ALL cold global loads up front (pos first, then x) ----
    const float* pp = pos + (sA + wv) * (NAG * 2);
    const float2 own = *(const float2*)(pp + 2 * ln);   // this lane's agent pos
    float4 pv[8];
    #pragma unroll
    for (int i = 0; i < 8; ++i) pv[i] = *(const float4*)(pp + 4 * i);

    const int r = t >> 2, co = (t & 3) * 16;
    const float* src = x + (sA * 16 + r) * 64 + co;
    const float4 v0 = *(const float4*)(src);
    const float4 v1 = *(const float4*)(src + 4);
    const float4 v2 = *(const float4*)(src + 8);
    const float4 v3 = *(const float4*)(src + 12);

    // L1 weight fragments + biases (L2-resident) prefetched across barrier-0
    short8 Brl1[2][2], Bro1[2][2];
    #pragma unroll
    for (int s = 0; s < 2; ++s) {
        Brl1[s][0] = ldfrag(ws, OFF_B1, 8, s + 2, n0, lane);
        Brl1[s][1] = ldfrag(ws, OFF_B1, 8, s + 2, n1, lane);
        Bro1[s][0] = ldfrag(ws, OFF_B1, 8, s, n0, lane);
        Bro1[s][1] = ldfrag(ws, OFF_B1, 8, s, n1, lane);
    }
    const float b10 = brel1[c0 + ln], b11 = brel1[c0 + 16 + ln];

    // ---- masks: per-wave (scene wv), register-resident pos, no serialization
    {
        unsigned m = 0;
        #pragma unroll
        for (int i = 0; i < 8; ++i) {
            const float dx0 = own.x - pv[i].x, dy0 = own.y - pv[i].y;
            const float dx1 = own.x - pv[i].z, dy1 = own.y - pv[i].w;
            if (dx0 * dx0 + dy0 * dy0 <= R2f && ln != 2 * i)     m |= 1u << (2 * i);
            if (dx1 * dx1 + dy1 * dy1 <= R2f && ln != 2 * i + 1) m |= 1u << (2 * i + 1);
        }
        if (q == 0) mask[wv * 16 + ln] = m;
    }

    // ---- stage x (f32->bf16) ----
    {
        uint4 ua, ub;
        ua.x = pk2(v0.x, v0.y); ua.y = pk2(v0.z, v0.w);
        ua.z = pk2(v1.x, v1.y); ua.w = pk2(v1.z, v1.w);
        ub.x = pk2(v2.x, v2.y); ub.y = pk2(v2.z, v2.w);
        ub.z = pk2(v3.x, v3.y); ub.w = pk2(v3.z, v3.w);
        *(uint4*)&xb[r * 136 + co]     = ua;
        *(uint4*)&xb[r * 136 + co + 8] = ub;
    }
    __syncthreads();

    short8 adjA[4];
    #pragma unroll
    for (int g = 0; g < 4; ++g) adjA[g] = make_adjA(mask[g * 16 + ln], q, g & 1);

    short8 Brl2[4][2];                        // prefetched mid-L1 for L2

    // ---- L1: x1 = relu(adj@(x@Wrel1) + x@Wroot1 + b1) -> x1b (pair-packed) ----
    {
        short8 Af[4][2];
        #pragma unroll
        for (int m = 0; m < 4; ++m) {               // y1 -> yT (no relu, no bias)
            Af[m][0] = *(const short8*)&xb[(m * 16 + ln) * 136 + q * 8];
            Af[m][1] = *(const short8*)&xb[(m * 16 + ln) * 136 + 32 + q * 8];
            f32x4 a0 = {0.f, 0.f, 0.f, 0.f}, a1 = a0;
            a0 = MFMA(Af[m][0], Brl1[0][0], a0); a0 = MFMA(Af[m][1], Brl1[1][0], a0);
            a1 = MFMA(Af[m][0], Brl1[0][1], a1); a1 = MFMA(Af[m][1], Brl1[1][1], a1);
            uint2 u0; u0.x = pk2(a0[0], a0[1]); u0.y = pk2(a0[2], a0[3]);
            uint2 u1; u1.x = pk2(a1[0], a1[1]); u1.y = pk2(a1[2], a1[3]);
            *(uint2*)&yT[(c0 + ln) * 72 + m * 16 + q * 4]      = u0;
            *(uint2*)&yT[(c0 + 16 + ln) * 72 + m * 16 + q * 4] = u1;
        }
        short8 By[2][2];
        #pragma unroll
        for (int w = 0; w < 2; ++w) {               // wave-local readback
            By[w][0] = *(const short8*)&yT[(c0 + ln) * 72 + w * 32 + q * 8];
            By[w][1] = *(const short8*)&yT[(c0 + 16 + ln) * 72 + w * 32 + q * 8];
        }
        #pragma unroll
        for (int s = 0; s < 4; ++s) {               // prefetch L2 rel weights
            Brl2[s][0] = ldfrag(ws, OFF_B2, 8, s + 4, n0, lane);
            Brl2[s][1] = ldfrag(ws, OFF_B2, 8, s + 4, n1, lane);
        }
        #pragma unroll
        for (int g = 0; g < 4; ++g) {
            f32x4 a0 = {b10, b10, b10, b10}, a1 = {b11, b11, b11, b11};
            a0 = MFMA(Af[g][0], Bro1[0][0], a0); a0 = MFMA(Af[g][1], Bro1[1][0], a0);
            a1 = MFMA(Af[g][0], Bro1[0][1], a1); a1 = MFMA(Af[g][1], Bro1[1][1], a1);
            a0 = MFMA(adjA[g], By[g >> 1][0], a0);
            a1 = MFMA(adjA[g], By[g >> 1][1], a1);
            #pragma unroll
            for (int r2 = 0; r2 < 4; ++r2) {
                const int row = g * 16 + q * 4 + r2;
                *(unsigned*)&x1b[row * 136 + c0 + 2 * ln] =
                    pk2(fmaxf(a0[r2], 0.f), fmaxf(a1[r2], 0.f));
            }
        }
    }
    __syncthreads();

    short8 Bf[8];                              // prefetched mid-L2 for GEMM3

    // ---- L2: x2 = relu(adj@(x1@Wrel2) + x1@Wroot2 + b2) -> xb (pair-packed) ----
    {
        const float b20 = brel2[c0 + ln], b21 = brel2[c0 + 16 + ln];
        short8 Bro2[4][2];
        #pragma unroll
        for (int s = 0; s < 4; ++s) {              // covered by m-loop below
            Bro2[s][0] = ldfrag(ws, OFF_B2, 8, s, n0, lane);
            Bro2[s][1] = ldfrag(ws, OFF_B2, 8, s, n1, lane);
        }
        #pragma unroll
        for (int m = 0; m < 4; ++m) {               // y2 -> yT
            f32x4 a0 = {0.f, 0.f, 0.f, 0.f}, a1 = a0;
            #pragma unroll
            for (int s = 0; s < 4; ++s) {
                const short8 A = *(const short8*)&x1b[(m * 16 + ln) * 136 + s * 32 + q * 8];
                a0 = MFMA(A, Brl2[s][0], a0);
                a1 = MFMA(A, Brl2[s][1], a1);
            }
            uint2 u0; u0.x = pk2(a0[0], a0[1]); u0.y = pk2(a0[2], a0[3]);
            uint2 u1; u1.x = pk2(a1[0], a1[1]); u1.y = pk2(a1[2], a1[3]);
            *(uint2*)&yT[(c0 + ln) * 72 + m * 16 + q * 4]      = u0;
            *(uint2*)&yT[(c0 + 16 + ln) * 72 + m * 16 + q * 4] = u1;
        }
        short8 By[2][2];
        #pragma unroll
        for (int w = 0; w < 2; ++w) {
            By[w][0] = *(const short8*)&yT[(c0 + ln) * 72 + w * 32 + q * 8];
            By[w][1] = *(const short8*)&yT[(c0 + 16 + ln) * 72 + w * 32 + q * 8];
        }
        #pragma unroll
        for (int s = 0; s < 8; ++s)                // prefetch GEMM3 weights
            Bf[s] = ldfrag(ws, OFF_H1, 4, s, wv, lane);
        #pragma unroll
        for (int g = 0; g < 4; ++g) {
            f32x4 a0 = {b20, b20, b20, b20}, a1 = {b21, b21, b21, b21};
            #pragma unroll
            for (int s = 0; s < 4; ++s) {
                const short8 A = *(const short8*)&x1b[(g * 16 + ln) * 136 + s * 32 + q * 8];
                a0 = MFMA(A, Bro2[s][0], a0);
                a1 = MFMA(A, Bro2[s][1], a1);
            }
            a0 = MFMA(adjA[g], By[g >> 1][0], a0);
            a1 = MFMA(adjA[g], By[g >> 1][1], a1);
            #pragma unroll
            for (int r2 = 0; r2 < 4; ++r2) {
                const int row = g * 16 + q * 4 + r2;
                *(unsigned*)&xb[row * 136 + c0 + 2 * ln] =
                    pk2(fmaxf(a0[r2], 0.f), fmaxf(a1[r2], 0.f));
            }
        }
    }
    __syncthreads();

    // ---- GEMM3: h1 = relu([x1|x2] @ Wh1 + bh1), n-tile = wv -> yT region ----
    short8 Bg2[2][2], Bg3;                     // prefetched here for GEMM4+5
    float hb2[2], hb3;
    {
        #pragma unroll
        for (int nt = 0; nt < 2; ++nt) {
            Bg2[0][nt] = ldfrag(ws, OFF_H2, 2, 0, nt, lane);
            Bg2[1][nt] = ldfrag(ws, OFF_H2, 2, 1, nt, lane);
        }
        Bg3 = ldfrag(ws, OFF_H3, 1, 0, 0, lane);
        hb2[0] = bh2[ln]; hb2[1] = bh2[16 + ln]; hb3 = bh3[ln];

        const float b = bh1[wv * 16 + ln];
        #pragma unroll
        for (int m = 0; m < 4; ++m) {
            f32x4 a = {b, b, b, b}, c = {0.f, 0.f, 0.f, 0.f};
            #pragma unroll
            for (int s = 0; s < 4; ++s) {
                const short8 A1 = *(const short8*)&x1b[(m * 16 + ln) * 136 + s * 32 + q * 8];
                const short8 A2 = *(const short8*)&xb[(m * 16 + ln) * 136 + s * 32 + q * 8];
                a = MFMA(A1, Bf[s], a);
                c = MFMA(A2, Bf[s + 4], c);
            }
            #pragma unroll
            for (int r2 = 0; r2 < 4; ++r2)
                yT[(m * 16 + q * 4 + r2) * 72 + wv * 16 + ln] = (u16)rb(fmaxf(a[r2] + c[r2], 0.f));
        }
    }
    __syncthreads();

    // ---- GEMM4+5 (wave-local: wave wv = scene wv): h2 then out ----
    {
        const u16* h1b = yT;
        u16* h2b = x1b;                              // x1 dead
        const short8 A0 = *(const short8*)&h1b[(wv * 16 + ln) * 72 + q * 8];
        const short8 A1 = *(const short8*)&h1b[(wv * 16 + ln) * 72 + 32 + q * 8];
        #pragma unroll
        for (int nt = 0; nt < 2; ++nt) {
            const float b = hb2[nt];
            f32x4 a = {b, b, b, b};
            a = MFMA(A0, Bg2[0][nt], a);
            a = MFMA(A1, Bg2[1][nt], a);
            #pragma unroll
            for (int r2 = 0; r2 < 4; ++r2)
                h2b[(wv * 16 + q * 4 + r2) * 40 + nt * 16 + ln] = (u16)rb(fmaxf(a[r2], 0.f));
        }
        const short8 A = *(const short8*)&h2b[(wv * 16 + ln) * 40 + q * 8];
        f32x4 a = {hb3, hb3, hb3, hb3};
        a = MFMA(A, Bg3, a);
        #pragma unroll
        for (int r2 = 0; r2 < 4; ++r2)
            out[(sA * 16 + wv * 16 + q * 4 + r2) * 16 + ln] = a[r2];
    }
}

extern "C" void kernel_launch(void* const* d_in, const int* in_sizes, int n_in,
                              void* d_out, int out_size, void* d_ws, size_t ws_size,
                              hipStream_t stream) {
    const float* x      = (const float*)d_in[0];
    const float* pos    = (const float*)d_in[1];
    const float* Wrel1  = (const float*)d_in[2];
    const float* brel1  = (const float*)d_in[3];
    const float* Wroot1 = (const float*)d_in[4];
    const float* Wrel2  = (const float*)d_in[5];
    const float* brel2  = (const float*)d_in[6];
    const float* Wroot2 = (const float*)d_in[7];
    const float* Wh1    = (const float*)d_in[8];
    const float* bh1    = (const float*)d_in[9];
    const float* Wh2    = (const float*)d_in[10];
    const float* bh2    = (const float*)d_in[11];
    const float* Wh3    = (const float*)d_in[12];
    const float* bh3    = (const float*)d_in[13];
    u16* ws = (u16*)d_ws;

    swizzle_w<<<(SWZ_UNITS + 255) / 256, 256, 0, stream>>>(
        Wrel1, Wroot1, Wrel2, Wroot2, Wh1, Wh2, Wh3, ws);
    gnn_fused5<<<NBLK, 256, 0, stream>>>(
        x, pos, brel1, brel2, bh1, bh2, bh3, ws, (float*)d_out);
}

// Round 4
// 121.686 us; speedup vs baseline: 1.0294x; 1.0294x over previous
//
#include <hip/hip_runtime.h>

#define NAG 16
#define SPB 4        // scenes per block, one M=64 batch, single pass
#define NBLK 2048
#define R2f 64.0f

typedef unsigned short u16;
typedef __attribute__((ext_vector_type(8))) short short8;
typedef __attribute__((ext_vector_type(4))) short short4v;
typedef __attribute__((ext_vector_type(4))) float f32x4;

#define MFMA(a, b, c)   __builtin_amdgcn_mfma_f32_16x16x32_bf16(a, b, c, 0, 0, 0)
#define MFMA16(a, b, c) __builtin_amdgcn_mfma_f32_16x16x16bf16_1k(a, b, c, 0, 0, 0)

// ws blob offsets in u16 units
#define OFF_B1 0        // [Wroot1;Wrel1]  K=128 N=128  S=4 T=8  (root s0..1, rel s2..3)
#define OFF_B2 16384    // [Wroot2;Wrel2]  K=256 N=128  S=8 T=8  (root s0..3, rel s4..7) [k-perm]
#define OFF_H1 49152    // Wh1             K=256 N=64   S=8 T=4                          [k-perm]
#define OFF_H2 65536    // Wh2             K=64  N=32   S=2 T=2
#define OFF_H3 67584    // Wh3             K=32  N=16   S=1 T=1
#define SWZ_UNITS 8512

__device__ __forceinline__ u16 f2b(float f) {            // RNE (swizzle only)
    unsigned u = __float_as_uint(f);
    unsigned r = u + 0x7FFFu + ((u >> 16) & 1u);
    return (u16)(r >> 16);
}
// fast round-to-nearest (ties up) — hot-kernel path; sub-ulp delta vs RNE
__device__ __forceinline__ unsigned rb(float f) {
    return (__float_as_uint(f) + 0x8000u) >> 16;
}
__device__ __forceinline__ unsigned pk2(float a, float b) {
    return ((__float_as_uint(a) + 0x8000u) >> 16) |
           ((__float_as_uint(b) + 0x8000u) & 0xFFFF0000u);
}

// ---------------- weight pre-swizzle: W[K][N] f32 -> fragment order bf16 -----
// B2/H1 use a k-permutation matching the pair-packed x1/x2 LDS layout:
// physical col p within each 32-group holds logical channel (p>>1) + 16*(p&1).
__global__ __launch_bounds__(256) void swizzle_w(
    const float* __restrict__ Wrel1, const float* __restrict__ Wroot1,
    const float* __restrict__ Wrel2, const float* __restrict__ Wroot2,
    const float* __restrict__ Wh1,  const float* __restrict__ Wh2,
    const float* __restrict__ Wh3,  u16* __restrict__ ws)
{
    const int u = blockIdx.x * 256 + threadIdx.x;
    if (u >= SWZ_UNITS) return;
    int v, T, N, ksplit;
    bool perm = false;
    const float *W, *W2;
    u16* dst;
    if (u < 2048)      { v = u;        T = 8; N = 128; ksplit = 64;  W = Wroot1; W2 = Wrel1; dst = ws + OFF_B1 + v * 8; }
    else if (u < 6144) { v = u - 2048; T = 8; N = 128; ksplit = 128; W = Wroot2; W2 = Wrel2; dst = ws + OFF_B2 + v * 8; perm = true; }
    else if (u < 8192) { v = u - 6144; T = 4; N = 64;  ksplit = 1 << 30; W = Wh1; W2 = Wh1; dst = ws + OFF_H1 + v * 8; perm = true; }
    else if (u < 8448) { v = u - 8192; T = 2; N = 32;  ksplit = 1 << 30; W = Wh2; W2 = Wh2; dst = ws + OFF_H2 + v * 8; }
    else               { v = u - 8448; T = 1; N = 16;  ksplit = 1 << 30; W = Wh3; W2 = Wh3; dst = ws + OFF_H3 + v * 8; }
    const int lane = v & 63;
    const int t = (v >> 6) % T;
    const int s = (v >> 6) / T;
    const int n = t * 16 + (lane & 15);
    const int k0 = s * 32 + (lane >> 4) * 8;
    #pragma unroll
    for (int j = 0; j < 8; ++j) {
        const int k = k0 + j;
        const int kl = perm ? ((k & ~31) + ((k & 31) >> 1) + ((k & 1) << 4)) : k;
        const float val = (kl < ksplit) ? W[kl * N + n] : W2[(kl - ksplit) * N + n];
        dst[j] = f2b(val);
    }
}

__device__ __forceinline__ short8 ldfrag(const u16* __restrict__ ws, int off,
                                         int T, int s, int tile, int lane) {
    return *(const short8*)(ws + off + (size_t)(((s * T + tile) * 64 + lane) * 8));
}

// adjacency as A-fragment of a 16x16x16 MFMA: A[m=ln][k=q*4+j] = adj[ln][q*4+j]
// (adj is symmetric, diag excluded). 2 VGPRs of bf16 {0,1}.
__device__ __forceinline__ short4v make_adjA16(unsigned m, int q) {
    union { short4v v; unsigned u[2]; } r;
    const int k0 = q * 4;
    r.u[0] = (((m >> (k0 + 0)) & 1u) ? 0x3F80u     : 0u) |
             (((m >> (k0 + 1)) & 1u) ? 0x3F800000u : 0u);
    r.u[1] = (((m >> (k0 + 2)) & 1u) ? 0x3F80u     : 0u) |
             (((m >> (k0 + 3)) & 1u) ? 0x3F800000u : 0u);
    return r.v;
}

// pk2'd D-fragment (uint2) -> B-operand of 16x16x16 MFMA.
// KEY IDENTITY (this round): the D-frag of a 16x16 MFMA (lane q,ln holds rows
// q*4+{0..3} of col ln) IS the B-frag layout of a 16x16x16 MFMA (k=q*4+{0..3},
// n=ln). So agg = adj @ y consumes the y accumulators DIRECTLY from registers:
// no LDS transpose round-trip (was: 8 ds_write_b64 + 4 ds_read_b128 + 2 full
// write->wait->read latency chains per wave per layer).
union P2B { uint2 u; short4v s; };

// LDS (u16 units): xb  [64][136] (x cols0..63; later x2 cols0..127)   0..8704
//                  h1r [64][72]  (h1 after GEMM3)                     8704..13312
//                  x1b [64][136] (x1; later h2 [64][40])              13312..22016
// 44.3 KB -> 3 blocks/CU. Barriers: S0|L1|L2|GEMM3|GEMM45 = 4.
// x1/x2 pair-packed (physical col p = logical (p>>1)+16*(p&1)); B2/H1 k-perm'd.
__global__ __launch_bounds__(256) void gnn_fused5(
    const float* __restrict__ x, const float* __restrict__ pos,
    const float* __restrict__ brel1, const float* __restrict__ brel2,
    const float* __restrict__ bh1,  const float* __restrict__ bh2,
    const float* __restrict__ bh3,
    const u16* __restrict__ ws, float* __restrict__ out)
{
    __shared__ __align__(16) u16 pool[22016];
    __shared__ unsigned mask[64];
    u16* const xb  = pool;          // also x2
    u16* const h1r = pool + 8704;   // h1
    u16* const x1b = pool + 13312;  // also h2

    const int t = threadIdx.x;
    const int wv = t >> 6, lane = t & 63, ln = lane & 15, q = lane >> 4;
    const int c0 = 32 * wv;                 // wave's output-col base (L1/L2)
    const int n0 = 2 * wv, n1 = 2 * wv + 1;
    const size_t sA = (size_t)blockIdx.x * SPB;

    // ---- S0: stage x (f32->bf16) + adjacency masks ----
    {
        const int r = t >> 2, co = (t & 3) * 16;
        const float* src = x + (sA * 16 + r) * 64 + co;
        const float4 v0 = *(const float4*)(src);
        const float4 v1 = *(const float4*)(src + 4);
        const float4 v2 = *(const float4*)(src + 8);
        const float4 v3 = *(const float4*)(src + 12);
        uint4 ua, ub;
        ua.x = pk2(v0.x, v0.y); ua.y = pk2(v0.z, v0.w);
        ua.z = pk2(v1.x, v1.y); ua.w = pk2(v1.z, v1.w);
        ub.x = pk2(v2.x, v2.y); ub.y = pk2(v2.z, v2.w);
        ub.z = pk2(v3.x, v3.y); ub.w = pk2(v3.z, v3.w);
        *(uint4*)&xb[r * 136 + co]     = ua;
        *(uint4*)&xb[r * 136 + co + 8] = ub;
    }
    if (t < 64) {
        const int g = t >> 4, a = t & 15;
        const float* pp = pos + (sA + g) * (NAG * 2);
        const float ax = pp[2 * a], ay = pp[2 * a + 1];
        unsigned m = 0;
        for (int j = 0; j < NAG; ++j) {
            const float dx = ax - pp[2 * j], dy = ay - pp[2 * j + 1];
            if (dx * dx + dy * dy <= R2f && j != a) m |= (1u << j);
        }
        mask[g * 16 + a] = m;
    }
    __syncthreads();

    short4v adjA16[4];
    #pragma unroll
    for (int g = 0; g < 4; ++g) adjA16[g] = make_adjA16(mask[g * 16 + ln], q);

    // ---- L1: x1 = relu(adj@(x@Wrel1) + x@Wroot1 + b1) -> x1b (pair-packed) ----
    {
        short8 Brl[2][2], Bro[2][2], Af[4][2];
        uint2 P0[4], P1[4];
        #pragma unroll
        for (int s = 0; s < 2; ++s) {
            Brl[s][0] = ldfrag(ws, OFF_B1, 8, s + 2, n0, lane);
            Brl[s][1] = ldfrag(ws, OFF_B1, 8, s + 2, n1, lane);
        }
        #pragma unroll
        for (int m = 0; m < 4; ++m) {               // y1 kept in registers (P)
            Af[m][0] = *(const short8*)&xb[(m * 16 + ln) * 136 + q * 8];
            Af[m][1] = *(const short8*)&xb[(m * 16 + ln) * 136 + 32 + q * 8];
            f32x4 a0 = {0.f, 0.f, 0.f, 0.f}, a1 = a0;
            a0 = MFMA(Af[m][0], Brl[0][0], a0); a0 = MFMA(Af[m][1], Brl[1][0], a0);
            a1 = MFMA(Af[m][0], Brl[0][1], a1); a1 = MFMA(Af[m][1], Brl[1][1], a1);
            P0[m].x = pk2(a0[0], a0[1]); P0[m].y = pk2(a0[2], a0[3]);
            P1[m].x = pk2(a1[0], a1[1]); P1[m].y = pk2(a1[2], a1[3]);
        }
        #pragma unroll
        for (int s = 0; s < 2; ++s) {
            Bro[s][0] = ldfrag(ws, OFF_B1, 8, s, n0, lane);
            Bro[s][1] = ldfrag(ws, OFF_B1, 8, s, n1, lane);
        }
        const float b0 = brel1[c0 + ln], b1 = brel1[c0 + 16 + ln];
        #pragma unroll
        for (int g = 0; g < 4; ++g) {
            f32x4 a0 = {b0, b0, b0, b0}, a1 = {b1, b1, b1, b1};
            a0 = MFMA(Af[g][0], Bro[0][0], a0); a0 = MFMA(Af[g][1], Bro[1][0], a0);
            a1 = MFMA(Af[g][0], Bro[0][1], a1); a1 = MFMA(Af[g][1], Bro[1][1], a1);
            P2B p0; p0.u = P0[g];
            P2B p1; p1.u = P1[g];
            a0 = MFMA16(adjA16[g], p0.s, a0);
            a1 = MFMA16(adjA16[g], p1.s, a1);
            #pragma unroll
            for (int r2 = 0; r2 < 4; ++r2) {
                const int row = g * 16 + q * 4 + r2;
                *(unsigned*)&x1b[row * 136 + c0 + 2 * ln] =
                    pk2(fmaxf(a0[r2], 0.f), fmaxf(a1[r2], 0.f));
            }
        }
    }
    __syncthreads();

    // ---- L2: x2 = relu(adj@(x1@Wrel2) + x1@Wroot2 + b2) -> xb (pair-packed) ----
    {
        short8 Brl[4][2];
        uint2 P0[4], P1[4];
        #pragma unroll
        for (int s = 0; s < 4; ++s) {
            Brl[s][0] = ldfrag(ws, OFF_B2, 8, s + 4, n0, lane);
            Brl[s][1] = ldfrag(ws, OFF_B2, 8, s + 4, n1, lane);
        }
        #pragma unroll
        for (int m = 0; m < 4; ++m) {               // y2 kept in registers (P)
            f32x4 a0 = {0.f, 0.f, 0.f, 0.f}, a1 = a0;
            #pragma unroll
            for (int s = 0; s < 4; ++s) {
                const short8 A = *(const short8*)&x1b[(m * 16 + ln) * 136 + s * 32 + q * 8];
                a0 = MFMA(A, Brl[s][0], a0);
                a1 = MFMA(A, Brl[s][1], a1);
            }
            P0[m].x = pk2(a0[0], a0[1]); P0[m].y = pk2(a0[2], a0[3]);
            P1[m].x = pk2(a1[0], a1[1]); P1[m].y = pk2(a1[2], a1[3]);
        }
        short8 Bro[4][2];
        #pragma unroll
        for (int s = 0; s < 4; ++s) {
            Bro[s][0] = ldfrag(ws, OFF_B2, 8, s, n0, lane);
            Bro[s][1] = ldfrag(ws, OFF_B2, 8, s, n1, lane);
        }
        const float b0 = brel2[c0 + ln], b1 = brel2[c0 + 16 + ln];
        #pragma unroll
        for (int g = 0; g < 4; ++g) {
            f32x4 a0 = {b0, b0, b0, b0}, a1 = {b1, b1, b1, b1};
            #pragma unroll
            for (int s = 0; s < 4; ++s) {
                const short8 A = *(const short8*)&x1b[(g * 16 + ln) * 136 + s * 32 + q * 8];
                a0 = MFMA(A, Bro[s][0], a0);
                a1 = MFMA(A, Bro[s][1], a1);
            }
            P2B p0; p0.u = P0[g];
            P2B p1; p1.u = P1[g];
            a0 = MFMA16(adjA16[g], p0.s, a0);
            a1 = MFMA16(adjA16[g], p1.s, a1);
            #pragma unroll
            for (int r2 = 0; r2 < 4; ++r2) {
                const int row = g * 16 + q * 4 + r2;
                *(unsigned*)&xb[row * 136 + c0 + 2 * ln] =
                    pk2(fmaxf(a0[r2], 0.f), fmaxf(a1[r2], 0.f));
            }
        }
    }
    __syncthreads();

    // ---- GEMM3: h1 = relu([x1|x2] @ Wh1 + bh1), n-tile = wv -> h1r ----
    {
        short8 Bf[8];
        #pragma unroll
        for (int s = 0; s < 8; ++s) Bf[s] = ldfrag(ws, OFF_H1, 4, s, wv, lane);
        const float b = bh1[wv * 16 + ln];
        #pragma unroll
        for (int m = 0; m < 4; ++m) {
            f32x4 a = {b, b, b, b}, c = {0.f, 0.f, 0.f, 0.f};
            #pragma unroll
            for (int s = 0; s < 4; ++s) {
                const short8 A1 = *(const short8*)&x1b[(m * 16 + ln) * 136 + s * 32 + q * 8];
                const short8 A2 = *(const short8*)&xb[(m * 16 + ln) * 136 + s * 32 + q * 8];
                a = MFMA(A1, Bf[s], a);
                c = MFMA(A2, Bf[s + 4], c);
            }
            #pragma unroll
            for (int r2 = 0; r2 < 4; ++r2)
                h1r[(m * 16 + q * 4 + r2) * 72 + wv * 16 + ln] = (u16)rb(fmaxf(a[r2] + c[r2], 0.f));
        }
    }
    __syncthreads();

    // ---- GEMM4+5 (wave-local: wave wv = scene wv): h2 then out ----
    {
        u16* h2b = x1b;                              // x1 dead
        const short8 A0 = *(const short8*)&h1r[(wv * 16 + ln) * 72 + q * 8];
        const short8 A1 = *(const short8*)&h1r[(wv * 16 + ln) * 72 + 32 + q * 8];
        #pragma unroll
        for (int nt = 0; nt < 2; ++nt) {
            const short8 B0 = ldfrag(ws, OFF_H2, 2, 0, nt, lane);
            const short8 B1 = ldfrag(ws, OFF_H2, 2, 1, nt, lane);
            const float b = bh2[nt * 16 + ln];
            f32x4 a = {b, b, b, b};
            a = MFMA(A0, B0, a);
            a = MFMA(A1, B1, a);
            #pragma unroll
            for (int r2 = 0; r2 < 4; ++r2)
                h2b[(wv * 16 + q * 4 + r2) * 40 + nt * 16 + ln] = (u16)rb(fmaxf(a[r2], 0.f));
        }
        const short8 A = *(const short8*)&h2b[(wv * 16 + ln) * 40 + q * 8];
        const short8 B = ldfrag(ws, OFF_H3, 1, 0, 0, lane);
        const float b = bh3[ln];
        f32x4 a = {b, b, b, b};
        a = MFMA(A, B, a);
        #pragma unroll
        for (int r2 = 0; r2 < 4; ++r2)
            out[(sA * 16 + wv * 16 + q * 4 + r2) * 16 + ln] = a[r2];
    }
}

extern "C" void kernel_launch(void* const* d_in, const int* in_sizes, int n_in,
                              void* d_out, int out_size, void* d_ws, size_t ws_size,
                              hipStream_t stream) {
    const float* x      = (const float*)d_in[0];
    const float* pos    = (const float*)d_in[1];
    const float* Wrel1  = (const float*)d_in[2];
    const float* brel1  = (const float*)d_in[3];
    const float* Wroot1 = (const float*)d_in[4];
    const float* Wrel2  = (const float*)d_in[5];
    const float* brel2  = (const float*)d_in[6];
    const float* Wroot2 = (const float*)d_in[7];
    const float* Wh1    = (const float*)d_in[8];
    const float* bh1    = (const float*)d_in[9];
    const float* Wh2    = (const float*)d_in[10];
    const float* bh2    = (const float*)d_in[11];
    const float* Wh3    = (const float*)d_in[12];
    const float* bh3    = (const float*)d_in[13];
    u16* ws = (u16*)d_ws;

    swizzle_w<<<(SWZ_UNITS + 255) / 256, 256, 0, stream>>>(
        Wrel1, Wroot1, Wrel2, Wroot2, Wh1, Wh2, Wh3, ws);
    gnn_fused5<<<NBLK, 256, 0, stream>>>(
        x, pos, brel1, brel2, bh1, bh2, bh3, ws, (float*)d_out);
}